// Round 7
// baseline (126.487 us; speedup 1.0000x reference)
//
#include <hip/hip_runtime.h>
#include <cstdint>

// B=4, N=256, D=128, HID=128, IN_DIM=516.
// G[i,j,h] = [|hi-hj| ; hi*hj] @ W1[256:512]  (K=256 fp8 MFMA, W x256) -- symmetric in (i,j)
// L[i,j] = relu(G/256 + PiB[i,h] + Pjf[j,h] + scal(i,j)·w) @ W2 + b2
// out[i,j] = out[j,i] = 0.5*(L[i,j]+L[j,i]) ; diag -1e9.
// R7: 16-node groups, 136 unordered tile-pairs x 4 batches = 544 blocks, 256 pairs/block.
//     M-split (2 phases of 128 pairs); N-split waves (32 h each) -> B = 32 VGPR/wave;
//     swizzled A-image (conflict-free); in-wave shfl h-reduction; direct symmetric stores.

typedef float f32x4 __attribute__((ext_vector_type(4)));

#define INV256 0.00390625f

// smem offsets (bytes)
#define SF_OFF 0                       // fp8 A-image: 8 ks x 4128 = 33024
#define SNODE_OFF 33024                // 32 rows x 128 fp32 = 16384
#define SPP_OFF 49408                  // 32 rows x 132 u32 {PiB,Pjf} = 16896
#define SCAL_OFF 66304                 // 256 pairs x uint4 (bf16 packed) = 4096
#define SPF_OFF 70400                  // 128 x 4 fp32 = 2048
#define SPM_OFF 72448                  // 128 x 4 fp32 = 2048
#define SMEM_TOTAL 74496

__device__ __forceinline__ uint32_t pk4(float a, float b, float c, float d) {
  uint32_t u = __builtin_amdgcn_cvt_pk_fp8_f32(a, b, 0, false);
  u = __builtin_amdgcn_cvt_pk_fp8_f32(c, d, u, true);
  return u;
}
__device__ __forceinline__ uint32_t pkbf2(float lo, float hi) {
  uint32_t l = __builtin_bit_cast(uint32_t, lo);
  uint32_t h = __builtin_bit_cast(uint32_t, hi);
  return (l >> 16) | (h & 0xffff0000u);
}
__device__ __forceinline__ float ulo(uint32_t u) {
  return __builtin_bit_cast(float, u << 16);
}
__device__ __forceinline__ float uhi(uint32_t u) {
  return __builtin_bit_cast(float, u & 0xffff0000u);
}
__device__ __forceinline__ long mk64(uint32_t lo, uint32_t hi) {
  return (long)((((unsigned long long)hi) << 32) | lo);
}

// bid<32: pack fp8 B-image (lane-linear MFMA fragment order, values W1*256)
// bid in [32,1056): PiB = node@W1[0:128] + b1 ; Pjf = node@W1[128:256]  (fp32)
__global__ __launch_bounds__(128) void pre_k(const float* __restrict__ node,
                                             const float* __restrict__ W1,
                                             const float* __restrict__ b1,
                                             float* __restrict__ PiB,
                                             float* __restrict__ Pjf,
                                             uint32_t* __restrict__ W1f8) {
  int bid = blockIdx.x;
  int tid = threadIdx.x;
  if (bid < 32) {
    int ks = bid >> 2, nip = (bid >> 1) & 1, wn = bid & 1;
    int lane = tid & 63, nilow = tid >> 6;
    int quad = lane >> 4, col = lane & 15;
    int h = wn * 64 + (nip * 2 + nilow) * 16 + col;
    int k0 = ks * 32 + quad * 8;
    float w[8];
#pragma unroll
    for (int t = 0; t < 8; ++t) w[t] = W1[(256 + k0 + t) * 128 + h] * 256.0f;
    uint2 u;
    u.x = pk4(w[0], w[1], w[2], w[3]);
    u.y = pk4(w[4], w[5], w[6], w[7]);
    reinterpret_cast<uint2*>(W1f8)[(bid * 64 + lane) * 2 + nilow] = u;
  } else {
    __shared__ float sN[128];
    int row = bid - 32;  // 0..1023
    int h = tid;
    sN[h] = node[row * 128 + h];
    __syncthreads();
    float ai = 0.f, aj = 0.f;
#pragma unroll 8
    for (int d = 0; d < 128; ++d) {
      float v = sN[d];
      ai = fmaf(v, W1[d * 128 + h], ai);
      aj = fmaf(v, W1[(128 + d) * 128 + h], aj);
    }
    PiB[row * 128 + h] = ai + b1[h];
    Pjf[row * 128 + h] = aj;
  }
}

// grid 544 = b(4) * 136 unordered 16-group pairs.
__global__ __launch_bounds__(256, 2) void main_k(
    const float* __restrict__ node, const float* __restrict__ baseL,
    const float* __restrict__ compL, const float* __restrict__ W1,
    const float* __restrict__ W2, const float* __restrict__ b2,
    const uint32_t* __restrict__ W1f8, const float* __restrict__ PiB,
    const float* __restrict__ Pjf, float* __restrict__ out) {
  __shared__ __align__(16) char smem[SMEM_TOTAL];
  char* sF = smem;
  float* sNode = reinterpret_cast<float*>(smem + SNODE_OFF);
  uint32_t* sPP = reinterpret_cast<uint32_t*>(smem + SPP_OFF);  // [32][132]
  uint4* sScal = reinterpret_cast<uint4*>(smem + SCAL_OFF);     // [256]
  float* sPF = reinterpret_cast<float*>(smem + SPF_OFF);        // [128][4]
  float* sPM = reinterpret_cast<float*>(smem + SPM_OFF);

  const int tid = threadIdx.x;
  const int bx = blockIdx.x;
  const int b = bx / 136;
  const int t = bx - b * 136;
  // decode unordered 16-group pair: off(x) = 16x - x(x-1)/2
  int tI = (int)((33.0f - sqrtf(1089.0f - 8.0f * (float)t)) * 0.5f);
  tI = (tI < 0) ? 0 : (tI > 15 ? 15 : tI);
  while ((16 * tI - ((tI * (tI - 1)) >> 1)) > t) --tI;
  while (tI < 15 && (16 * (tI + 1) - (((tI + 1) * tI) >> 1)) <= t) ++tI;
  const int tJ = tI + (t - (16 * tI - ((tI * (tI - 1)) >> 1)));
  const int I0 = tI * 16, J0 = tJ * 16;
  const int rowB = b * 256;

  const int lane = tid & 63;
  const int wn2 = tid >> 6;  // wave: owns h-cols wn2*32..wn2*32+31
  const int col = lane & 15, quad = lane >> 4;

  // ---- B-fragments to registers: one uint4 per ks (2 ni tiles), held all kernel ----
  const int uB = ((wn2 & 1) << 1) | (wn2 >> 1);
  uint4 gB[8];
#pragma unroll
  for (int ks = 0; ks < 8; ++ks)
    gB[ks] = reinterpret_cast<const uint4*>(W1f8)[(ks * 4 + uB) * 64 + lane];

  // ---- stage 32 node rows fp32 (rows 0-15: I-group, 16-31: J-group) ----
#pragma unroll
  for (int it = 0; it < 4; ++it) {
    int idx = it * 256 + tid;
    int row = idx >> 5, d4 = idx & 31;
    int gr = rowB + ((row < 16) ? (I0 + row) : (J0 + row - 16));
    reinterpret_cast<float4*>(sNode)[row * 32 + d4] =
        reinterpret_cast<const float4*>(node + (size_t)gr * 128)[d4];
  }

  // ---- stage PP: u32 = {bf16 PiB | bf16 Pjf} per (row, h) ----
#pragma unroll
  for (int it = 0; it < 4; ++it) {
    int idx = it * 256 + tid;
    int row = idx >> 5, d4 = idx & 31;
    int gr = rowB + ((row < 16) ? (I0 + row) : (J0 + row - 16));
    float4 a = reinterpret_cast<const float4*>(PiB + (size_t)gr * 128)[d4];
    float4 c = reinterpret_cast<const float4*>(Pjf + (size_t)gr * 128)[d4];
    uint4 u;
    u.x = pkbf2(a.x, c.x);
    u.y = pkbf2(a.y, c.y);
    u.z = pkbf2(a.z, c.z);
    u.w = pkbf2(a.w, c.w);
    *reinterpret_cast<uint4*>(&sPP[row * 132 + d4 * 4]) = u;
  }

  // ---- stage scalar features for all 256 pairs (fwd + mirror), bf16-packed ----
  {
    int p = tid;
    int iN = I0 + (p >> 4), jN = J0 + (p & 15);
    float blf = fminf(fmaxf(baseL[(size_t)(rowB + iN) * 256 + jN], -20.f), 20.f);
    float clf = fminf(fmaxf(compL[(size_t)(rowB + iN) * 256 + jN], -20.f), 20.f);
    float blm = fminf(fmaxf(baseL[(size_t)(rowB + jN) * 256 + iN], -20.f), 20.f);
    float clm = fminf(fmaxf(compL[(size_t)(rowB + jN) * 256 + iN], -20.f), 20.f);
    uint4 u;
    u.x = pkbf2(blf, 1.f / (1.f + __expf(-blf)));
    u.y = pkbf2(clf, 1.f / (1.f + __expf(-clf)));
    u.z = pkbf2(blm, 1.f / (1.f + __expf(-blm)));
    u.w = pkbf2(clm, 1.f / (1.f + __expf(-clm)));
    sScal[p] = u;
  }

  // ---- per-lane epilogue constants (2 ni columns) ----
  float cB0[2], cB1[2], cB2[2], cB3[2], cW2[2];
#pragma unroll
  for (int ni = 0; ni < 2; ++ni) {
    int h = (wn2 * 2 + ni) * 16 + col;
    cB0[ni] = W1[512 * 128 + h];
    cB1[ni] = W1[513 * 128 + h];
    cB2[ni] = W1[514 * 128 + h];
    cB3[ni] = W1[515 * 128 + h];
    cW2[ni] = W2[h];
  }
  const float b2v = b2[0];
  __syncthreads();

  // ================= two M-phases of 128 pairs =================
#pragma unroll 1
  for (int H = 0; H < 2; ++H) {
    // ---- F-build: 128 pairs x 256 k fp8, swizzled A-fragment image ----
    {
      const int d4 = tid & 31;
      const int rr = tid >> 5;  // 0..7
      const int ks1 = d4 >> 3, qd = (d4 >> 1) & 3, kb = (d4 & 1) * 4;
#pragma unroll
      for (int js = 0; js < 2; ++js) {
        int jj = rr + js * 8;
        const float4 hj = reinterpret_cast<const float4*>(sNode)[(16 + jj) * 32 + d4];
        int scol = ((jj + 2 * qd) & 15);
        uint32_t base = ks1 * 4128 + qd * 128 + scol * 8 + kb;
#pragma unroll
        for (int iiL = 0; iiL < 8; ++iiL) {
          const float4 hi = reinterpret_cast<const float4*>(sNode)[(H * 8 + iiL) * 32 + d4];
          uint32_t du = pk4(fabsf(hi.x - hj.x), fabsf(hi.y - hj.y),
                            fabsf(hi.z - hj.z), fabsf(hi.w - hj.w));
          uint32_t pu = pk4(hi.x * hj.x, hi.y * hj.y, hi.z * hj.z, hi.w * hj.w);
          uint32_t addr = base + iiL * 512;
          *reinterpret_cast<uint32_t*>(sF + addr) = du;
          *reinterpret_cast<uint32_t*>(sF + addr + 4 * 4128) = pu;
        }
      }
    }
    __syncthreads();

    // ---- MFMA: 128 pairs x 32 h (this wave), K=256 ----
    f32x4 acc[8][2] = {};
    const int ascol = ((col + 2 * quad) & 15);
    const char* aBase = sF + quad * 128 + ascol * 8;
#pragma unroll
    for (int ks = 0; ks < 8; ++ks) {
      long bb0 = mk64(gB[ks].x, gB[ks].y);
      long bb1 = mk64(gB[ks].z, gB[ks].w);
#pragma unroll
      for (int mi = 0; mi < 8; ++mi) {
        uint2 av = *reinterpret_cast<const uint2*>(aBase + ks * 4128 + mi * 512);
        long aa = mk64(av.x, av.y);
        acc[mi][0] = __builtin_amdgcn_mfma_f32_16x16x32_fp8_fp8(aa, bb0, acc[mi][0], 0, 0, 0);
        acc[mi][1] = __builtin_amdgcn_mfma_f32_16x16x32_fp8_fp8(aa, bb1, acc[mi][1], 0, 0, 0);
      }
    }
    __syncthreads();  // A-image reads done; next phase may rebuild sF

    // ---- epilogue: fwd + mirror, in-wave h-reduction via shfl ----
    uint32_t ppJ[4][2];
#pragma unroll
    for (int r = 0; r < 4; ++r)
#pragma unroll
      for (int ni = 0; ni < 2; ++ni)
        ppJ[r][ni] = sPP[(16 + quad * 4 + r) * 132 + (wn2 * 2 + ni) * 16 + col];

#pragma unroll
    for (int mi = 0; mi < 8; ++mi) {
      const int iiF = H * 8 + mi;
      float piI[2], pjI[2];
#pragma unroll
      for (int ni = 0; ni < 2; ++ni) {
        uint32_t u = sPP[iiF * 132 + (wn2 * 2 + ni) * 16 + col];
        piI[ni] = ulo(u);
        pjI[ni] = uhi(u);
      }
#pragma unroll
      for (int r = 0; r < 4; ++r) {
        int p = mi * 16 + quad * 4 + r;
        uint4 sc = sScal[p];
        float f0 = ulo(sc.x), f1 = uhi(sc.x), f2 = ulo(sc.y), f3 = uhi(sc.y);
        float m0 = ulo(sc.z), m1 = uhi(sc.z), m2 = ulo(sc.w), m3 = uhi(sc.w);
        float vf = 0.f, vm = 0.f;
#pragma unroll
        for (int ni = 0; ni < 2; ++ni) {
          float piJ = ulo(ppJ[r][ni]), pjJ = uhi(ppJ[r][ni]);
          float gv = acc[mi][ni][r] * INV256;
          float pf = (gv + piI[ni]) + pjJ;
          pf = fmaf(f0, cB0[ni], pf);
          pf = fmaf(f1, cB1[ni], pf);
          pf = fmaf(f2, cB2[ni], pf);
          pf = fmaf(f3, cB3[ni], pf);
          float pm = (gv + piJ) + pjI[ni];
          pm = fmaf(m0, cB0[ni], pm);
          pm = fmaf(m1, cB1[ni], pm);
          pm = fmaf(m2, cB2[ni], pm);
          pm = fmaf(m3, cB3[ni], pm);
          vf = fmaf(fmaxf(pf, 0.f), cW2[ni], vf);
          vm = fmaf(fmaxf(pm, 0.f), cW2[ni], vm);
        }
        vf += __shfl_xor(vf, 1);
        vf += __shfl_xor(vf, 2);
        vf += __shfl_xor(vf, 4);
        vf += __shfl_xor(vf, 8);
        vm += __shfl_xor(vm, 1);
        vm += __shfl_xor(vm, 2);
        vm += __shfl_xor(vm, 4);
        vm += __shfl_xor(vm, 8);
        if (col == 0) {
          sPF[p * 4 + wn2] = vf;
          sPM[p * 4 + wn2] = vm;
        }
      }
    }
    __syncthreads();

    // ---- final: combine 4 wave-partials, symmetric store ----
    if (tid < 128) {
      int p = tid;
      float4 pf4 = reinterpret_cast<const float4*>(sPF)[p];
      float4 pm4 = reinterpret_cast<const float4*>(sPM)[p];
      float val = 0.5f * ((pf4.x + pf4.y + pf4.z + pf4.w) +
                          (pm4.x + pm4.y + pm4.z + pm4.w)) + b2v;
      int iN = I0 + H * 8 + (p >> 4);
      int jN = J0 + (p & 15);
      if (iN == jN) val = -1e9f;
      out[(size_t)(rowB + iN) * 256 + jN] = val;
      out[(size_t)(rowB + jN) * 256 + iN] = val;
    }
    __syncthreads();  // sPF/sPM reads done before next phase's epilogue writes
  }
}

extern "C" void kernel_launch(void* const* d_in, const int* in_sizes, int n_in,
                              void* d_out, int out_size, void* d_ws, size_t ws_size,
                              hipStream_t stream) {
  const float* node = (const float*)d_in[0];   // [4,256,128]
  const float* baseL = (const float*)d_in[1];  // [4,256,256]
  const float* compL = (const float*)d_in[2];  // [4,256,256]
  const float* W1 = (const float*)d_in[3];     // [516,128]
  const float* b1 = (const float*)d_in[4];     // [128]
  const float* W2 = (const float*)d_in[5];     // [128,1]
  const float* b2 = (const float*)d_in[6];     // [1]
  float* out = (float*)d_out;                  // [4,256,256] fp32

  char* ws = (char*)d_ws;
  float* PiB = (float*)(ws);                        // 512 KB
  float* Pjf = (float*)(ws + (512 << 10));          // 512 KB
  uint32_t* W1f8 = (uint32_t*)(ws + (1024 << 10));  // 32 KB

  pre_k<<<1056, 128, 0, stream>>>(node, W1, b1, PiB, Pjf, W1f8);
  main_k<<<544, 256, 0, stream>>>(node, baseL, compL, W1, W2, b2, W1f8, PiB, Pjf, out);
}

// Round 8
// 94.527 us; speedup vs baseline: 1.3381x; 1.3381x over previous
//
#include <hip/hip_runtime.h>
#include <cstdint>

// B=4, N=256, D=128, HID=128, IN_DIM=516.
// G[i,j,h] = [|hi-hj| ; hi*hj] @ W1[256:512]  (K=256 fp8 MFMA, W x256) -- symmetric in (i,j)
// pre' = 256*pre = acc + PiB'[i,h] + Pjf'[j,h] + scal'(i,j)·w   (PiB',Pjf',scal' pre-scaled x256)
// L = relu(pre') @ (W2/256) + b2   (relu positively homogeneous -> no per-element descale)
// out[i,j] = out[j,i] = 0.5*(L_f + L_m) ; diag -1e9.
// R8 = R6 grid (2112 blocks, 64 pairs) + R7's register-B + swizzled sF (+ks-rotation),
//      no sNode (global L1), LDS 25.9KB -> 5 blocks/CU, LB(256,5).

typedef float f32x4 __attribute__((ext_vector_type(4)));

#define INV256 0.00390625f

__device__ __forceinline__ uint32_t pk4(float a, float b, float c, float d) {
  uint32_t u = __builtin_amdgcn_cvt_pk_fp8_f32(a, b, 0, false);
  u = __builtin_amdgcn_cvt_pk_fp8_f32(c, d, u, true);
  return u;
}
__device__ __forceinline__ uint32_t pkbf2(float lo, float hi) {
  uint32_t l = __builtin_bit_cast(uint32_t, lo);
  uint32_t h = __builtin_bit_cast(uint32_t, hi);
  return (l >> 16) | (h & 0xffff0000u);
}
__device__ __forceinline__ float ulo(uint32_t u) {
  return __builtin_bit_cast(float, u << 16);
}
__device__ __forceinline__ float uhi(uint32_t u) {
  return __builtin_bit_cast(float, u & 0xffff0000u);
}
__device__ __forceinline__ long mk64(uint32_t lo, uint32_t hi) {
  return (long)((((unsigned long long)hi) << 32) | lo);
}

// bid<32: pack fp8 B-image (lane-linear MFMA fragment order, values W1*256)
// bid in [32,1056): PiB' = 256*(node@W1[0:128] + b1) ; Pjf' = 256*(node@W1[128:256])
__global__ __launch_bounds__(128) void pre_k(const float* __restrict__ node,
                                             const float* __restrict__ W1,
                                             const float* __restrict__ b1,
                                             float* __restrict__ PiB,
                                             float* __restrict__ Pjf,
                                             uint32_t* __restrict__ W1f8) {
  int bid = blockIdx.x;
  int tid = threadIdx.x;
  if (bid < 32) {
    int ks = bid >> 2, nip = (bid >> 1) & 1, wn = bid & 1;
    int lane = tid & 63, nilow = tid >> 6;
    int quad = lane >> 4, col = lane & 15;
    int h = wn * 64 + (nip * 2 + nilow) * 16 + col;
    int k0 = ks * 32 + quad * 8;
    float w[8];
#pragma unroll
    for (int t = 0; t < 8; ++t) w[t] = W1[(256 + k0 + t) * 128 + h] * 256.0f;
    uint2 u;
    u.x = pk4(w[0], w[1], w[2], w[3]);
    u.y = pk4(w[4], w[5], w[6], w[7]);
    reinterpret_cast<uint2*>(W1f8)[(bid * 64 + lane) * 2 + nilow] = u;
  } else {
    __shared__ float sN[128];
    int row = bid - 32;  // 0..1023
    int h = tid;
    sN[h] = node[row * 128 + h];
    __syncthreads();
    float ai = 0.f, aj = 0.f;
#pragma unroll 8
    for (int d = 0; d < 128; ++d) {
      float v = sN[d];
      ai = fmaf(v, W1[d * 128 + h], ai);
      aj = fmaf(v, W1[(128 + d) * 128 + h], aj);
    }
    PiB[row * 128 + h] = 256.0f * (ai + b1[h]);
    Pjf[row * 128 + h] = 256.0f * aj;
  }
}

// grid 2112 = b(4) * 528 unordered 8-group pairs (I<=J). 64 pairs/block, K=256 fp8.
// waves: wn2 = tid>>6 owns h-cols [wn2*32, wn2*32+32) (ni tiles 2wn2, 2wn2+1).
__global__ __launch_bounds__(256, 5) void main_k(
    const float* __restrict__ node, const float* __restrict__ baseL,
    const float* __restrict__ compL, const float* __restrict__ W1,
    const float* __restrict__ W2, const float* __restrict__ b2,
    const uint32_t* __restrict__ W1f8, const float* __restrict__ PiB,
    const float* __restrict__ Pjf, float* __restrict__ out) {
  // sF: [ks 0..7][mi 0..3][q 0..3][scol 0..15] 8B, scol=(col+2q+4(ks&3))&15 -> 16384 B
  //   (overlaid post-MFMA by sP: [64 pairs][40] fp32 partials, fwd@0..15, mir@20..35)
  // sPP: [16 rows][132] u32 {bf16 PiB' | bf16 Pjf'} (rows 0-7 I-group, 8-15 J-group)
  // sScal: [64 pairs] uint4 bf16x2 {bl',sig'}{cl',sig'} fwd then mirror
  __shared__ __align__(16) char smem[16384 + 8448 + 1024];
  char* sF = smem;
  uint32_t* sPP = reinterpret_cast<uint32_t*>(smem + 16384);
  uint4* sScal = reinterpret_cast<uint4*>(smem + 16384 + 8448);
  float* sP = reinterpret_cast<float*>(smem);  // overlay

  const int tid = threadIdx.x;
  const int bx = blockIdx.x;
  const int b = bx / 528;
  const int t = bx - b * 528;
  int tI = (int)((65.0f - sqrtf(4225.0f - 8.0f * (float)t)) * 0.5f);
  tI = (tI < 0) ? 0 : (tI > 31 ? 31 : tI);
  while (((65 * tI - tI * tI) >> 1) > t) --tI;
  while (tI < 31 && ((65 * (tI + 1) - (tI + 1) * (tI + 1)) >> 1) <= t) ++tI;
  const int tJ = tI + (t - ((65 * tI - tI * tI) >> 1));
  const int I0 = tI * 8, J0 = tJ * 8;
  const int rowB = b * 256;

  const int lane = tid & 63;
  const int wn2 = tid >> 6;
  const int col = lane & 15, quad = lane >> 4;

  // ---- B-fragments to registers (32 VGPR), L2-broadcast, held all kernel ----
  const int uB = ((wn2 & 1) << 1) | (wn2 >> 1);
  uint4 gB[8];
#pragma unroll
  for (int ks = 0; ks < 8; ++ks)
    gB[ks] = reinterpret_cast<const uint4*>(W1f8)[(ks * 4 + uB) * 64 + lane];

  // ---- stage sPP: 16 rows x 128 u32 {PiB'|Pjf'} bf16-packed, coalesced ----
#pragma unroll
  for (int it = 0; it < 2; ++it) {
    int fidx = it * 256 + tid;  // 512 float4 slots
    int row = fidx >> 5, d4 = fidx & 31;
    int gr = rowB + ((row < 8) ? (I0 + row) : (J0 + row - 8));
    float4 a = reinterpret_cast<const float4*>(PiB + (size_t)gr * 128)[d4];
    float4 c = reinterpret_cast<const float4*>(Pjf + (size_t)gr * 128)[d4];
    uint4 u;
    u.x = pkbf2(a.x, c.x);
    u.y = pkbf2(a.y, c.y);
    u.z = pkbf2(a.z, c.z);
    u.w = pkbf2(a.w, c.w);
    *reinterpret_cast<uint4*>(&sPP[row * 132 + d4 * 4]) = u;
  }

  // ---- stage scal (x256), fwd (tid<64) and mirror (tid in [64,128)) ----
  if (tid < 128) {
    int p = tid & 63, dir = tid >> 6;
    int iN = I0 + (p >> 3), jN = J0 + (p & 7);
    int rr = dir ? jN : iN, cc = dir ? iN : jN;
    float bl = fminf(fmaxf(baseL[(size_t)(rowB + rr) * 256 + cc], -20.f), 20.f);
    float cl = fminf(fmaxf(compL[(size_t)(rowB + rr) * 256 + cc], -20.f), 20.f);
    uint2 u;
    u.x = pkbf2(256.f * bl, 256.f / (1.f + __expf(-bl)));
    u.y = pkbf2(256.f * cl, 256.f / (1.f + __expf(-cl)));
    *reinterpret_cast<uint2*>(reinterpret_cast<char*>(&sScal[p]) + dir * 8) = u;
  }

  // ---- per-lane epilogue constants (2 ni columns) ----
  float cB0[2], cB1[2], cB2[2], cB3[2], cW2[2];
#pragma unroll
  for (int ni = 0; ni < 2; ++ni) {
    int h = (wn2 * 2 + ni) * 16 + col;
    cB0[ni] = W1[512 * 128 + h];
    cB1[ni] = W1[513 * 128 + h];
    cB2[ni] = W1[514 * 128 + h];
    cB3[ni] = W1[515 * 128 + h];
    cW2[ni] = W2[h] * INV256;
  }
  const float b2v = b2[0];

  // ---- F-build: 64 pairs x 256 k fp8, node read direct from global (L1-hot) ----
  {
    const int d4 = tid & 31;  // float4 index in 128 dims
    const int rr = tid >> 5;  // j-row 0..7
    const int ks1 = d4 >> 3, qd = (d4 >> 1) & 3, kb = (d4 & 1) * 4;
    const int scolbase = 2 * qd + 4 * ks1;  // ks-rotation -> 2-way (free) write conflicts
    const float4 hj = *reinterpret_cast<const float4*>(node + (size_t)(rowB + J0 + rr) * 128 + d4 * 4);
#pragma unroll
    for (int ii = 0; ii < 8; ++ii) {
      const float4 hi = *reinterpret_cast<const float4*>(node + (size_t)(rowB + I0 + ii) * 128 + d4 * 4);
      uint32_t du = pk4(fabsf(hi.x - hj.x), fabsf(hi.y - hj.y),
                        fabsf(hi.z - hj.z), fabsf(hi.w - hj.w));
      uint32_t pu = pk4(hi.x * hj.x, hi.y * hj.y, hi.z * hj.z, hi.w * hj.w);
      int p = ii * 8 + rr;
      int colp = p & 15, mi = p >> 4;
      int scol = (colp + scolbase) & 15;
      uint32_t addr = mi * 512 + qd * 128 + scol * 8 + kb;
      *reinterpret_cast<uint32_t*>(sF + ks1 * 2048 + addr) = du;
      *reinterpret_cast<uint32_t*>(sF + (ks1 + 4) * 2048 + addr) = pu;
    }
  }
  __syncthreads();

  // ---- MFMA: acc[4 mi][2 ni], K=256; A from swizzled LDS, B from registers ----
  f32x4 acc[4][2] = {};
#pragma unroll
  for (int ks = 0; ks < 8; ++ks) {
    long bb0 = mk64(gB[ks].x, gB[ks].y);
    long bb1 = mk64(gB[ks].z, gB[ks].w);
    const int ascol = (col + 2 * quad + 4 * (ks & 3)) & 15;
    const char* aks = sF + ks * 2048 + quad * 128 + ascol * 8;
#pragma unroll
    for (int mi = 0; mi < 4; ++mi) {
      uint2 av = *reinterpret_cast<const uint2*>(aks + mi * 512);
      long aa = mk64(av.x, av.y);
      acc[mi][0] = __builtin_amdgcn_mfma_f32_16x16x32_fp8_fp8(aa, bb0, acc[mi][0], 0, 0, 0);
      acc[mi][1] = __builtin_amdgcn_mfma_f32_16x16x32_fp8_fp8(aa, bb1, acc[mi][1], 0, 0, 0);
    }
  }
  __syncthreads();  // sF reads done -> sP overlay writable

  // ---- epilogue: fwd+mirror, partial shfl reduce (xor 1,2), 4 partials/wave ----
  uint32_t uJ[4][2];
#pragma unroll
  for (int r = 0; r < 4; ++r)
#pragma unroll
    for (int ni = 0; ni < 2; ++ni)
      uJ[r][ni] = sPP[(8 + (quad & 1) * 4 + r) * 132 + (wn2 * 2 + ni) * 16 + col];

#pragma unroll
  for (int mi = 0; mi < 4; ++mi) {
    const int ii = mi * 2 + (quad >> 1);
    uint32_t uI[2];
#pragma unroll
    for (int ni = 0; ni < 2; ++ni)
      uI[ni] = sPP[ii * 132 + (wn2 * 2 + ni) * 16 + col];
#pragma unroll
    for (int r = 0; r < 4; ++r) {
      int p = mi * 16 + quad * 4 + r;  // C/D: pair row = quad*4 + r
      uint4 sc = sScal[p];
      float f0 = ulo(sc.x), f1 = uhi(sc.x), f2 = ulo(sc.y), f3 = uhi(sc.y);
      float m0 = ulo(sc.z), m1 = uhi(sc.z), m2 = ulo(sc.w), m3 = uhi(sc.w);
      float vf = 0.f, vm = 0.f;
#pragma unroll
      for (int ni = 0; ni < 2; ++ni) {
        float piI = ulo(uI[ni]), pjI = uhi(uI[ni]);
        float piJ = ulo(uJ[r][ni]), pjJ = uhi(uJ[r][ni]);
        float a = acc[mi][ni][r];
        float pf = (a + piI) + pjJ;
        pf = fmaf(f0, cB0[ni], pf);
        pf = fmaf(f1, cB1[ni], pf);
        pf = fmaf(f2, cB2[ni], pf);
        pf = fmaf(f3, cB3[ni], pf);
        float pm = (a + piJ) + pjI;
        pm = fmaf(m0, cB0[ni], pm);
        pm = fmaf(m1, cB1[ni], pm);
        pm = fmaf(m2, cB2[ni], pm);
        pm = fmaf(m3, cB3[ni], pm);
        vf = fmaf(fmaxf(pf, 0.f), cW2[ni], vf);
        vm = fmaf(fmaxf(pm, 0.f), cW2[ni], vm);
      }
      vf += __shfl_xor(vf, 1);
      vf += __shfl_xor(vf, 2);
      vm += __shfl_xor(vm, 1);
      vm += __shfl_xor(vm, 2);
      if ((col & 3) == 0) {
        int part = wn2 * 4 + (col >> 2);
        sP[p * 40 + part] = vf;
        sP[p * 40 + 20 + part] = vm;
      }
    }
  }
  __syncthreads();

  // ---- final: sum 16 fwd + 16 mirror partials, symmetric store ----
  if (tid < 64) {
    int p = tid;
    const float4* pf4 = reinterpret_cast<const float4*>(sP + p * 40);
    const float4* pm4 = reinterpret_cast<const float4*>(sP + p * 40 + 20);
    float4 fa = pf4[0], fb = pf4[1], fc = pf4[2], fd = pf4[3];
    float4 ma = pm4[0], mb = pm4[1], mc = pm4[2], md = pm4[3];
    float sumF = (fa.x + fa.y + fa.z + fa.w) + (fb.x + fb.y + fb.z + fb.w) +
                 (fc.x + fc.y + fc.z + fc.w) + (fd.x + fd.y + fd.z + fd.w);
    float sumM = (ma.x + ma.y + ma.z + ma.w) + (mb.x + mb.y + mb.z + mb.w) +
                 (mc.x + mc.y + mc.z + mc.w) + (md.x + md.y + md.z + md.w);
    float val = 0.5f * (sumF + sumM) + b2v;
    int iN = I0 + (p >> 3), jN = J0 + (p & 7);
    if (iN == jN) val = -1e9f;
    out[(size_t)(rowB + iN) * 256 + jN] = val;
    out[(size_t)(rowB + jN) * 256 + iN] = val;
  }
}

extern "C" void kernel_launch(void* const* d_in, const int* in_sizes, int n_in,
                              void* d_out, int out_size, void* d_ws, size_t ws_size,
                              hipStream_t stream) {
  const float* node = (const float*)d_in[0];   // [4,256,128]
  const float* baseL = (const float*)d_in[1];  // [4,256,256]
  const float* compL = (const float*)d_in[2];  // [4,256,256]
  const float* W1 = (const float*)d_in[3];     // [516,128]
  const float* b1 = (const float*)d_in[4];     // [128]
  const float* W2 = (const float*)d_in[5];     // [128,1]
  const float* b2 = (const float*)d_in[6];     // [1]
  float* out = (float*)d_out;                  // [4,256,256] fp32

  char* ws = (char*)d_ws;
  float* PiB = (float*)(ws);                        // 512 KB
  float* Pjf = (float*)(ws + (512 << 10));          // 512 KB
  uint32_t* W1f8 = (uint32_t*)(ws + (1024 << 10));  // 32 KB

  pre_k<<<1056, 128, 0, stream>>>(node, W1, b1, PiB, Pjf, W1f8);
  main_k<<<2112, 256, 0, stream>>>(node, baseL, compL, W1, W2, b2, W1f8, PiB, Pjf, out);
}